// Round 1
// baseline (8803.963 us; speedup 1.0000x reference)
//
#include <hip/hip_runtime.h>
#include <hip/hip_bf16.h>

// ---------------------------------------------------------------------------
// GPT-2 small forward: B=4 S=1024 L=12 D=768 H=12 DK=64 DFF=3072 V=50257
// Strategy: fp32 residual stream in workspace; bf16 MFMA GEMMs (convert at
// LDS staging); flash-style MFMA attention; fp32 LN/softmax.
// ---------------------------------------------------------------------------

typedef __bf16 bf16;
typedef bf16 bf16x8 __attribute__((ext_vector_type(8)));
typedef bf16 bf16x4 __attribute__((ext_vector_type(4)));
typedef float f32x4 __attribute__((ext_vector_type(4)));

#define MFMA_BF16(a, b, c) __builtin_amdgcn_mfma_f32_16x16x32_bf16((a), (b), (c), 0, 0, 0)

#define NTOK 4096
#define DIM 768
#define DFF_ 3072
#define NHEAD 12
#define DK_ 64
#define SEQ 1024
#define VOCAB 50257
#define NLAYER 12

__device__ __forceinline__ float gelu_exact(float v) {
    return 0.5f * v * (1.0f + erff(v * 0.70710678118654752f));
}

// ---------------------------------------------------------------------------
// Embedding: x[n,:] = wte[idx[n],:] + wpe[n % S,:]
// ---------------------------------------------------------------------------
__global__ __launch_bounds__(256) void embed_kernel(const int* __restrict__ idx,
                                                    const float* __restrict__ wte,
                                                    const float* __restrict__ wpe,
                                                    float* __restrict__ x) {
    int n = blockIdx.x;
    int t = idx[n];
    int s = n & (SEQ - 1);
    size_t xo = (size_t)n * DIM;
    size_t to = (size_t)t * DIM;
    size_t so = (size_t)s * DIM;
    for (int d = threadIdx.x; d < DIM; d += 256)
        x[xo + d] = wte[to + d] + wpe[so + d];
}

// ---------------------------------------------------------------------------
// LayerNorm: one block (256 threads) per token, D=768 (3 elems/thread)
// ---------------------------------------------------------------------------
__global__ __launch_bounds__(256) void ln_kernel(const float* __restrict__ in,
                                                 float* __restrict__ out,
                                                 const float* __restrict__ w,
                                                 const float* __restrict__ b) {
    int n = blockIdx.x;
    int tid = threadIdx.x;
    const float* row = in + (size_t)n * DIM;
    float x0 = row[tid], x1 = row[tid + 256], x2 = row[tid + 512];
    float s = x0 + x1 + x2;
    float sq = x0 * x0 + x1 * x1 + x2 * x2;
#pragma unroll
    for (int off = 32; off > 0; off >>= 1) {
        s += __shfl_down(s, off);
        sq += __shfl_down(sq, off);
    }
    __shared__ float sw[4], sqw[4];
    int wv = tid >> 6;
    if ((tid & 63) == 0) { sw[wv] = s; sqw[wv] = sq; }
    __syncthreads();
    s = sw[0] + sw[1] + sw[2] + sw[3];
    sq = sqw[0] + sqw[1] + sqw[2] + sqw[3];
    float mean = s * (1.0f / 768.0f);
    float var = sq * (1.0f / 768.0f) - mean * mean;
    float inv = rsqrtf(var + 1e-5f);
    float* orow = out + (size_t)n * DIM;
    orow[tid]       = (x0 - mean) * inv * w[tid]       + b[tid];
    orow[tid + 256] = (x1 - mean) * inv * w[tid + 256] + b[tid + 256];
    orow[tid + 512] = (x2 - mean) * inv * w[tid + 512] + b[tid + 512];
}

// ---------------------------------------------------------------------------
// bf16 MFMA GEMM: C[M,N] = A[M,K] @ B[K,N]  (BT: B stored [N,K], i.e. B^T)
// A,B fp32 in global, converted to bf16 at LDS staging; fp32 accumulate.
// 128x128 tile, BK=32, 256 threads = 4 waves (2x2), each wave 64x64 = 4x4
// tiles of mfma_f32_16x16x32_bf16.
// EPI: 0 = plain store, 1 = +R residual, 2 = exact GELU.
// M assumed multiple of 128 (4096 here); K multiple of 32; N multiple of 4
// (BT path guards n >= N for the 50257 head).
// ---------------------------------------------------------------------------
template <int EPI, bool BT>
__global__ __launch_bounds__(256) void gemm_kernel(const float* __restrict__ A,
                                                   const float* __restrict__ B,
                                                   const float* __restrict__ R,
                                                   float* __restrict__ C,
                                                   int M, int N, int K) {
    (void)M;
    __shared__ __align__(16) bf16 As[128][40]; // +8 pad keeps 16B align, breaks bank stride
    __shared__ __align__(16) bf16 Bs[128][40]; // stored [n][k] so B-frag reads are contiguous
    const int m0 = blockIdx.x * 128;
    const int n0 = blockIdx.y * 128;
    const int tid = threadIdx.x;
    const int lane = tid & 63;
    const int wave = tid >> 6;
    const int wm = (wave >> 1) * 64;
    const int wn = (wave & 1) * 64;
    const int quad = lane >> 4;
    const int r16 = lane & 15;

    f32x4 acc[4][4] = {};

    const int ra = tid >> 3, ca = (tid & 7) * 4;   // A/BT staging: 128 rows x 32 cols
    const int kb = tid >> 5, nb = (tid & 31) * 4;  // B-NN staging: 32 rows x 128 cols

    for (int k0 = 0; k0 < K; k0 += 32) {
        // ---- stage A tile [128 x 32] fp32 -> bf16 ----
#pragma unroll
        for (int i = 0; i < 4; i++) {
            int r = ra + 32 * i;
            float4 v = *(const float4*)&A[(size_t)(m0 + r) * K + (k0 + ca)];
            bf16x4 t;
            t[0] = (bf16)v.x; t[1] = (bf16)v.y; t[2] = (bf16)v.z; t[3] = (bf16)v.w;
            *(bf16x4*)&As[r][ca] = t;
        }
        // ---- stage B tile into [n][k] layout ----
        if (BT) {
#pragma unroll
            for (int i = 0; i < 4; i++) {
                int r = ra + 32 * i;
                int gn = n0 + r;
                float4 v;
                if (gn < N) v = *(const float4*)&B[(size_t)gn * K + (k0 + ca)];
                else { v.x = v.y = v.z = v.w = 0.f; }
                bf16x4 t;
                t[0] = (bf16)v.x; t[1] = (bf16)v.y; t[2] = (bf16)v.z; t[3] = (bf16)v.w;
                *(bf16x4*)&Bs[r][ca] = t;
            }
        } else {
#pragma unroll
            for (int i = 0; i < 4; i++) {
                int kk = kb + 8 * i;
                float4 v = *(const float4*)&B[(size_t)(k0 + kk) * N + (n0 + nb)];
                Bs[nb + 0][kk] = (bf16)v.x;
                Bs[nb + 1][kk] = (bf16)v.y;
                Bs[nb + 2][kk] = (bf16)v.z;
                Bs[nb + 3][kk] = (bf16)v.w;
            }
        }
        __syncthreads();
        // ---- fragments + MFMA ----
        bf16x8 af[4], bfr[4];
#pragma unroll
        for (int t = 0; t < 4; t++) {
            af[t]  = *(const bf16x8*)&As[wm + t * 16 + r16][quad * 8];
            bfr[t] = *(const bf16x8*)&Bs[wn + t * 16 + r16][quad * 8];
        }
#pragma unroll
        for (int tm = 0; tm < 4; tm++)
#pragma unroll
            for (int tn = 0; tn < 4; tn++)
                acc[tm][tn] = MFMA_BF16(af[tm], bfr[tn], acc[tm][tn]);
        __syncthreads();
    }

    // ---- epilogue: C row = quad*4+i, col = lane&15 ----
#pragma unroll
    for (int tm = 0; tm < 4; tm++) {
        int rb_ = m0 + wm + tm * 16 + quad * 4;
#pragma unroll
        for (int tn = 0; tn < 4; tn++) {
            int col = n0 + wn + tn * 16 + r16;
            if (BT && col >= N) continue;
#pragma unroll
            for (int i = 0; i < 4; i++) {
                size_t off = (size_t)(rb_ + i) * N + col;
                float v = acc[tm][tn][i];
                if constexpr (EPI == 1) v += R[off];
                if constexpr (EPI == 2) v = gelu_exact(v);
                C[off] = v;
            }
        }
    }
}

// ---------------------------------------------------------------------------
// Flash attention: block per (qtile=64 rows, head, batch). 256 threads.
// q,k,v are fp32 [4096, 768] with head h at cols h*64..h*64+63.
// Online softmax in fp32 through LDS; QK^T and PV via bf16 MFMA.
// ---------------------------------------------------------------------------
__global__ __launch_bounds__(256) void attn_kernel(const float* __restrict__ Qm,
                                                   const float* __restrict__ Km,
                                                   const float* __restrict__ Vm,
                                                   float* __restrict__ Om) {
    const int qt = blockIdx.x;  // 0..15
    const int h  = blockIdx.y;  // 0..11
    const int b  = blockIdx.z;  // 0..3
    const int tid = threadIdx.x;
    const int lane = tid & 63;
    const int wave = tid >> 6;
    const int quad = lane >> 4;
    const int r16 = lane & 15;
    const size_t base = (size_t)b * SEQ * DIM + h * DK_;

    __shared__ __align__(16) bf16 Qs[64][72];
    __shared__ __align__(16) bf16 Ks[64][72];
    __shared__ __align__(16) bf16 VsT[64][72]; // [d][kv] so PV B-frag is contiguous
    __shared__ __align__(16) bf16 Ps[64][72];
    __shared__ float Sc[64][66];
    __shared__ float pm[64][4], psum[64][4];
    __shared__ float mstate[64], lstate[64], alphas[64];

    // stage Q tile [64 x 64]
    {
        int r = tid >> 2, cb0 = (tid & 3) * 16;
        const float* qrow = Qm + base + (size_t)(qt * 64 + r) * DIM;
#pragma unroll
        for (int i = 0; i < 4; i++) {
            int c = cb0 + i * 4;
            float4 v = *(const float4*)&qrow[c];
            bf16x4 t;
            t[0] = (bf16)v.x; t[1] = (bf16)v.y; t[2] = (bf16)v.z; t[3] = (bf16)v.w;
            *(bf16x4*)&Qs[r][c] = t;
        }
    }
    if (tid < 64) { mstate[tid] = -1e30f; lstate[tid] = 0.f; }
    f32x4 accO[4] = {};
    __syncthreads();

    for (int j = 0; j <= qt; j++) {
        // stage K, V tiles
        {
            int r = tid >> 2, cb0 = (tid & 3) * 16;
            const float* krow = Km + base + (size_t)(j * 64 + r) * DIM;
            const float* vrow = Vm + base + (size_t)(j * 64 + r) * DIM;
#pragma unroll
            for (int i = 0; i < 4; i++) {
                int c = cb0 + i * 4;
                float4 kv = *(const float4*)&krow[c];
                bf16x4 t;
                t[0] = (bf16)kv.x; t[1] = (bf16)kv.y; t[2] = (bf16)kv.z; t[3] = (bf16)kv.w;
                *(bf16x4*)&Ks[r][c] = t;
                float4 vv = *(const float4*)&vrow[c];
                VsT[c + 0][r] = (bf16)vv.x;
                VsT[c + 1][r] = (bf16)vv.y;
                VsT[c + 2][r] = (bf16)vv.z;
                VsT[c + 3][r] = (bf16)vv.w;
            }
        }
        __syncthreads();

        // scores: wave w handles q rows w*16..w*16+15, all 64 k cols
        bf16x8 qa0 = *(const bf16x8*)&Qs[wave * 16 + r16][quad * 8];
        bf16x8 qa1 = *(const bf16x8*)&Qs[wave * 16 + r16][32 + quad * 8];
#pragma unroll
        for (int t = 0; t < 4; t++) {
            f32x4 sc = {};
            bf16x8 kb0 = *(const bf16x8*)&Ks[t * 16 + r16][quad * 8];
            sc = MFMA_BF16(qa0, kb0, sc);
            bf16x8 kb1 = *(const bf16x8*)&Ks[t * 16 + r16][32 + quad * 8];
            sc = MFMA_BF16(qa1, kb1, sc);
            int kcol = t * 16 + r16;
            int gk = j * 64 + kcol;
#pragma unroll
            for (int i = 0; i < 4; i++) {
                int row = wave * 16 + quad * 4 + i;
                int gq = qt * 64 + row;
                Sc[row][kcol] = (gk <= gq) ? sc[i] * 0.125f : -1e30f;
            }
        }
        __syncthreads();

        // partial max (4 threads per row, 16 cols each)
        {
            int r = tid >> 2, p0 = (tid & 3) * 16;
            float mx = -1e30f;
#pragma unroll
            for (int c = 0; c < 16; c++) mx = fmaxf(mx, Sc[r][p0 + c]);
            pm[r][tid & 3] = mx;
        }
        __syncthreads();
        if (tid < 64) {
            float mnew = fmaxf(fmaxf(pm[tid][0], pm[tid][1]), fmaxf(pm[tid][2], pm[tid][3]));
            mnew = fmaxf(mnew, mstate[tid]);
            alphas[tid] = __expf(mstate[tid] - mnew);
            mstate[tid] = mnew;
        }
        __syncthreads();
        // exp + partial sums + P (bf16)
        {
            int r = tid >> 2, p0 = (tid & 3) * 16;
            float mnew = mstate[r];
            float sum = 0.f;
#pragma unroll
            for (int c = 0; c < 16; c++) {
                float p = __expf(Sc[r][p0 + c] - mnew);
                sum += p;
                Ps[r][p0 + c] = (bf16)p;
            }
            psum[r][tid & 3] = sum;
        }
        __syncthreads();
        if (tid < 64)
            lstate[tid] = lstate[tid] * alphas[tid] +
                          psum[tid][0] + psum[tid][1] + psum[tid][2] + psum[tid][3];
        // rescale O and accumulate PV
        float al[4];
#pragma unroll
        for (int i = 0; i < 4; i++) al[i] = alphas[wave * 16 + quad * 4 + i];
#pragma unroll
        for (int t = 0; t < 4; t++)
#pragma unroll
            for (int i = 0; i < 4; i++) accO[t][i] *= al[i];
#pragma unroll
        for (int kk = 0; kk < 2; kk++) {
            bf16x8 pa = *(const bf16x8*)&Ps[wave * 16 + r16][kk * 32 + quad * 8];
#pragma unroll
            for (int t = 0; t < 4; t++) {
                bf16x8 vb = *(const bf16x8*)&VsT[t * 16 + r16][kk * 32 + quad * 8];
                accO[t] = MFMA_BF16(pa, vb, accO[t]);
            }
        }
        __syncthreads();
    }

    // write O / lstate
    float linv[4];
#pragma unroll
    for (int i = 0; i < 4; i++) linv[i] = 1.0f / lstate[wave * 16 + quad * 4 + i];
#pragma unroll
    for (int t = 0; t < 4; t++) {
        int col = t * 16 + r16;
#pragma unroll
        for (int i = 0; i < 4; i++) {
            int row = qt * 64 + wave * 16 + quad * 4 + i;
            Om[base + (size_t)row * DIM + col] = accO[t][i] * linv[i];
        }
    }
}

// ---------------------------------------------------------------------------
extern "C" void kernel_launch(void* const* d_in, const int* in_sizes, int n_in,
                              void* d_out, int out_size, void* d_ws, size_t ws_size,
                              hipStream_t stream) {
    (void)in_sizes; (void)n_in; (void)out_size; (void)ws_size;
    const int*   idx  = (const int*)d_in[0];
    const float* wte  = (const float*)d_in[1];
    const float* wpe  = (const float*)d_in[2];
    const float* ln1w = (const float*)d_in[3];
    const float* ln1b = (const float*)d_in[4];
    const float* wq   = (const float*)d_in[5];
    const float* wk   = (const float*)d_in[6];
    const float* wv   = (const float*)d_in[7];
    const float* wo   = (const float*)d_in[8];
    const float* ln2w = (const float*)d_in[9];
    const float* ln2b = (const float*)d_in[10];
    const float* fc1  = (const float*)d_in[11];
    const float* fc2  = (const float*)d_in[12];
    const float* lnfw = (const float*)d_in[13];
    const float* lnfb = (const float*)d_in[14];
    float* out = (float*)d_out;
    float* ws = (float*)d_ws;

    const size_t ND = (size_t)NTOK * DIM;
    float* x  = ws;
    float* hb = ws + ND;
    float* q  = ws + 2 * ND;
    float* k  = ws + 3 * ND;
    float* v  = ws + 4 * ND;
    float* ao = ws + 5 * ND;
    float* u  = ws + 6 * ND; // [4096, 3072]

    embed_kernel<<<NTOK, 256, 0, stream>>>(idx, wte, wpe, x);

    for (int l = 0; l < NLAYER; l++) {
        const size_t DD = (size_t)DIM * DIM;
        const size_t DF = (size_t)DIM * DFF_;
        ln_kernel<<<NTOK, 256, 0, stream>>>(x, hb, ln1w + l * DIM, ln1b + l * DIM);
        gemm_kernel<0, false><<<dim3(32, 6), 256, 0, stream>>>(hb, wq + l * DD, nullptr, q, NTOK, DIM, DIM);
        gemm_kernel<0, false><<<dim3(32, 6), 256, 0, stream>>>(hb, wk + l * DD, nullptr, k, NTOK, DIM, DIM);
        gemm_kernel<0, false><<<dim3(32, 6), 256, 0, stream>>>(hb, wv + l * DD, nullptr, v, NTOK, DIM, DIM);
        attn_kernel<<<dim3(16, NHEAD, 4), 256, 0, stream>>>(q, k, v, ao);
        gemm_kernel<1, false><<<dim3(32, 6), 256, 0, stream>>>(ao, wo + l * DD, x, x, NTOK, DIM, DIM);
        ln_kernel<<<NTOK, 256, 0, stream>>>(x, hb, ln2w + l * DIM, ln2b + l * DIM);
        gemm_kernel<2, false><<<dim3(32, 24), 256, 0, stream>>>(hb, fc1 + l * DF, nullptr, u, NTOK, DFF_, DIM);
        gemm_kernel<1, false><<<dim3(32, 6), 256, 0, stream>>>(u, fc2 + l * DF, x, x, NTOK, DIM, DFF_);
    }

    ln_kernel<<<NTOK, 256, 0, stream>>>(x, hb, lnfw, lnfb);
    // tied head: logits = h @ wte^T, wte is [V, D] (BT layout)
    gemm_kernel<0, true><<<dim3(32, 393), 256, 0, stream>>>(hb, wte, nullptr, out, NTOK, VOCAB, DIM);
}